// Round 5
// baseline (713.660 us; speedup 1.0000x reference)
//
#include <hip/hip_runtime.h>

#define IMG_H 512
#define IMG_W 512
#define TILE_COLS 256               // output cols per block
#define TILE_ROWS 8                 // output rows per block
#define HALO 5
#define VCOLS (TILE_COLS + 2*HALO)  // 266 columns produced by vertical stage
#define NTHREADS 256                // 4 waves
#define VSTRIDE_P 268               // h2 elements per row (row = 1072 B, 16B-aligned)
#define NROWS_IN (TILE_ROWS + 2*HALO)  // 18 input rows
#define NSLOTS 64                   // hashed f64 accumulator slots (64B stride)

typedef _Float16 h2 __attribute__((ext_vector_type(2)));

// Gaussian(sigma=1.5), 11 taps, normalized
static constexpr float GW[11] = {
    0.00102838f, 0.00759876f, 0.03600077f, 0.10936053f, 0.21300556f,
    0.26601170f,
    0.21300556f, 0.10936053f, 0.03600077f, 0.00759876f, 0.00102838f
};

__device__ __forceinline__ h2 wsplat(int t) {
    return h2{(_Float16)GW[t], (_Float16)GW[t]};
}

// Vertical 11-tap conv for one column v of the tile.
// Two packed channels: p0 = (x, y), p1 = (x^2+y^2, x*y).
// Results (8 output rows) -> vb[ch][r][v].
__device__ __forceinline__ void vertical_col(
    int v, int c0, int y0, size_t pbase,
    const float* __restrict__ den, const float* __restrict__ cln,
    h2 (*vb)[TILE_ROWS][VSTRIDE_P]) {
    const int gc = c0 - HALO + v;
    const bool colok = (gc >= 0) && (gc < IMG_W);

    h2 p0[NROWS_IN], p1[NROWS_IN];
#pragma unroll
    for (int i = 0; i < NROWS_IN; ++i) {
        const int gr = y0 - HALO + i;
        const bool ok = colok && ((unsigned)gr < (unsigned)IMG_H);
        float x = 0.f, y = 0.f;
        if (ok) {
            const size_t idx = pbase + (size_t)gr * IMG_W + gc;
            x = den[idx]; y = cln[idx];
        }
        x = fminf(fmaxf(x, 0.f), 1.f);   // v_med3_f32
        y = fminf(fmaxf(y, 0.f), 1.f);
        const float s = fmaf(x, x, y * y);   // x^2 + y^2
        const float p = x * y;
        p0[i] = h2{(_Float16)x, (_Float16)y};
        p1[i] = h2{(_Float16)s, (_Float16)p};
    }

    h2 am[TILE_ROWS], aq[TILE_ROWS];
#pragma unroll
    for (int r = 0; r < TILE_ROWS; ++r) {
        am[r] = h2{(_Float16)0.f, (_Float16)0.f};
        aq[r] = h2{(_Float16)0.f, (_Float16)0.f};
    }
#pragma unroll
    for (int i = 0; i < NROWS_IN; ++i) {
#pragma unroll
        for (int r = 0; r < TILE_ROWS; ++r) {
            const int t = i - r;
            if (t >= 0 && t <= 10) {
                const h2 w = wsplat(t);
                am[r] = __builtin_elementwise_fma(p0[i], w, am[r]);  // v_pk_fma_f16
                aq[r] = __builtin_elementwise_fma(p1[i], w, aq[r]);
            }
        }
    }
#pragma unroll
    for (int r = 0; r < TILE_ROWS; ++r) {
        vb[0][r][v] = am[r];
        vb[1][r][v] = aq[r];
    }
}

__global__ __launch_bounds__(NTHREADS, 4)   // R4's (,8) clamped VGPR to 32 -> scratch spill, 3.5x regression
void ssim_fused(const float* __restrict__ den, const float* __restrict__ cln,
                double* __restrict__ slots, unsigned* __restrict__ counter,
                float* __restrict__ out, double inv_n) {
    __shared__ __align__(16) h2 vbuf[2][TILE_ROWS][VSTRIDE_P]; // 17,152 B
    __shared__ float red[NTHREADS/64];

    const int tid = threadIdx.x;
    const int b  = blockIdx.x;
    const int cs    = b & 1;          // 2 col strips
    const int rs    = (b >> 1) & 63;  // 64 row strips
    const int plane = b >> 7;         // 96 planes

    const int c0 = cs * TILE_COLS;
    const int y0 = rs * TILE_ROWS;
    const size_t pbase = (size_t)plane * (IMG_H * IMG_W);

    // ---- vertical stage: 266 cols over 256 threads (wave 0 lanes 0..9 do two) ----
    vertical_col(tid, c0, y0, pbase, den, cln, vbuf);
    if (tid < VCOLS - NTHREADS)
        vertical_col(NTHREADS + tid, c0, y0, pbase, den, cln, vbuf);
    __syncthreads();

    // ---- horizontal stage + SSIM: 512 items = exactly 2 per thread ----
    float ssim_acc = 0.f;
#pragma unroll
    for (int s = 0; s < 2; ++s) {
        const int item = tid + NTHREADS * s;
        const int row = item >> 6;          // 0..7
        const int j   = (item & 63) << 2;   // start col (h2 units), 16B-aligned
        h2 cm[16], cq[16];
#pragma unroll
        for (int v = 0; v < 4; ++v) {       // 4x ds_read_b128 per channel
            *(uint4*)&cm[4*v] = *(const uint4*)&vbuf[0][row][j + 4*v];
            *(uint4*)&cq[4*v] = *(const uint4*)&vbuf[1][row][j + 4*v];
        }
#pragma unroll
        for (int o = 0; o < 4; ++o) {
            h2 am = h2{(_Float16)0.f, (_Float16)0.f};
            h2 aq = h2{(_Float16)0.f, (_Float16)0.f};
#pragma unroll
            for (int t = 0; t < 11; ++t) {
                const h2 w = wsplat(t);
                am = __builtin_elementwise_fma(cm[o + t], w, am);
                aq = __builtin_elementwise_fma(cq[o + t], w, aq);
            }
            const float mu1 = (float)am.x, mu2 = (float)am.y;
            const float eq  = (float)aq.x, ep = (float)aq.y;
            const float C1 = 1e-4f, C2 = 9e-4f;
            const float mu1s = mu1*mu1, mu2s = mu2*mu2, mu12 = mu1*mu2;
            const float ssum = eq - mu1s - mu2s;   // sigma1_sq + sigma2_sq
            const float s12  = ep - mu12;
            const float num = fmaf(2.f, mu12, C1) * fmaf(2.f, s12, C2);
            const float dnm = (mu1s + mu2s + C1) * (ssum + C2);
            ssim_acc = fmaf(num, __builtin_amdgcn_rcpf(dnm), ssim_acc);
        }
    }

    // ---- block reduction -> hashed slot; last block finalizes ----
#pragma unroll
    for (int off = 32; off > 0; off >>= 1)
        ssim_acc += __shfl_down(ssim_acc, off, 64);
    if ((tid & 63) == 0) red[tid >> 6] = ssim_acc;
    __syncthreads();
    if (tid == 0) {
        float s = red[0] + red[1] + red[2] + red[3];
        atomicAdd(&slots[(size_t)(b & (NSLOTS - 1)) * 8], (double)s);
        __threadfence();
        const unsigned old = atomicAdd(counter, 1u);
        if (old == gridDim.x - 1) {
            volatile double* vs = slots;   // bypass L1 — slots written via L2 atomics
            double t = 0.0;
            for (int i = 0; i < NSLOTS; ++i) t += vs[i * 8];
            out[0] = 1.0f - (float)(t * inv_n);
        }
    }
}

extern "C" void kernel_launch(void* const* d_in, const int* in_sizes, int n_in,
                              void* d_out, int out_size, void* d_ws, size_t ws_size,
                              hipStream_t stream) {
    const float* den = (const float*)d_in[0];
    const float* cln = (const float*)d_in[1];
    float* out = (float*)d_out;
    double* slots = (double*)d_ws;
    unsigned* counter = (unsigned*)((char*)d_ws + NSLOTS * 64);

    // zero slots + counter (ws re-poisoned to 0xAA before every timed launch)
    hipMemsetAsync(d_ws, 0, NSLOTS * 64 + 64, stream);

    const int n = in_sizes[0];                 // 32*3*512*512
    const int planes = n / (IMG_H * IMG_W);    // 96
    dim3 grid(planes * 2 * 64);                // 2 col strips x 64 row strips
    ssim_fused<<<grid, NTHREADS, 0, stream>>>(den, cln, slots, counter, out,
                                              1.0 / (double)n);
}

// Round 6
// 292.961 us; speedup vs baseline: 2.4360x; 2.4360x over previous
//
#include <hip/hip_runtime.h>

#define IMG_H 512
#define IMG_W 512
#define TILE_COLS 256               // output cols per block
#define TILE_ROWS 8                 // output rows per block
#define HALO 5
#define VCOLS (TILE_COLS + 2*HALO)  // 266 columns produced by vertical stage
#define NTHREADS 256                // 4 waves
#define VSTRIDE2 272                // halfs per row (544 B, 16B-aligned)
#define NROWS_IN (TILE_ROWS + 2*HALO)  // 18 input rows
#define NCH 4                       // blurred channels: x, y, x^2+y^2, x*y
#define NSLOTS 64                   // hashed f64 accumulator slots (64B stride)

typedef _Float16 h2 __attribute__((ext_vector_type(2)));

// Gaussian(sigma=1.5), 11 taps, normalized
#define W0 0.00102838f
#define W1 0.00759876f
#define W2 0.03600077f
#define W3 0.10936053f
#define W4 0.21300556f
#define W5 0.26601170f

static constexpr float GW[11] = { W0,W1,W2,W3,W4,W5,W4,W3,W2,W1,W0 };

// weight pairs for fdot2: even outputs use [w0..w10,0], odd use [0,w0..w10]
static __device__ const h2 WEVEN[6] = {
    {(_Float16)W0,(_Float16)W1},{(_Float16)W2,(_Float16)W3},{(_Float16)W4,(_Float16)W5},
    {(_Float16)W4,(_Float16)W3},{(_Float16)W2,(_Float16)W1},{(_Float16)W0,(_Float16)0.f}
};
static __device__ const h2 WODD[6] = {
    {(_Float16)0.f,(_Float16)W0},{(_Float16)W1,(_Float16)W2},{(_Float16)W3,(_Float16)W4},
    {(_Float16)W5,(_Float16)W4},{(_Float16)W3,(_Float16)W2},{(_Float16)W1,(_Float16)W0}
};

// Horizontal 11-tap conv producing 4 consecutive outputs from 16 halfs at pp
// (8-byte aligned). f32 accumulation via v_dot2_f32_f16.
__device__ __forceinline__ void hconv4h(const _Float16* __restrict__ pp, float out[4]) {
    union { uint2 u2[4]; h2 p[8]; _Float16 h[16]; } w;
#pragma unroll
    for (int v = 0; v < 4; ++v) w.u2[v] = *(const uint2*)(pp + 4*v);
#if __has_builtin(__builtin_amdgcn_fdot2)
#pragma unroll
    for (int o = 0; o < 4; ++o) {
        const int base = o >> 1;
        float s = 0.f;
        if (o & 1) {
#pragma unroll
            for (int t = 0; t < 6; ++t)
                s = __builtin_amdgcn_fdot2(w.p[base + t], WODD[t], s, false);
        } else {
#pragma unroll
            for (int t = 0; t < 6; ++t)
                s = __builtin_amdgcn_fdot2(w.p[base + t], WEVEN[t], s, false);
        }
        out[o] = s;
    }
#else
    float f[16];
#pragma unroll
    for (int i = 0; i < 16; ++i) f[i] = (float)w.h[i];
#pragma unroll
    for (int o = 0; o < 4; ++o) {
        float s = 0.f;
#pragma unroll
        for (int t = 0; t < 11; ++t) s = fmaf(GW[t], f[o+t], s);
        out[o] = s;
    }
#endif
}

// Vertical 11-tap conv of {x, y, x^2+y^2, x*y} for one column v, 8 output rows.
// f32 accumulation (R3-proven codegen), f16 store to LDS.
__device__ __forceinline__ void vertical_col(
    int v, int c0, int y0, size_t pbase,
    const float* __restrict__ den, const float* __restrict__ cln,
    _Float16 (*vbuf)[TILE_ROWS][VSTRIDE2]) {
    const int gc = c0 - HALO + v;
    const bool colok = (gc >= 0) && (gc < IMG_W);

    float xv[NROWS_IN], yv[NROWS_IN];
#pragma unroll
    for (int i = 0; i < NROWS_IN; ++i) {
        const int gr = y0 - HALO + i;
        const bool ok = colok && ((unsigned)gr < (unsigned)IMG_H);
        float x = 0.f, y = 0.f;
        if (ok) {
            const size_t idx = pbase + (size_t)gr * IMG_W + gc;
            x = den[idx]; y = cln[idx];
        }
        xv[i] = x; yv[i] = y;
    }

    float a0[TILE_ROWS], a1[TILE_ROWS], a2[TILE_ROWS], a3[TILE_ROWS];
#pragma unroll
    for (int r = 0; r < TILE_ROWS; ++r) { a0[r]=a1[r]=a2[r]=a3[r]=0.f; }
#pragma unroll
    for (int i = 0; i < NROWS_IN; ++i) {
        const float x = fminf(fmaxf(xv[i], 0.f), 1.f);   // v_med3_f32
        const float y = fminf(fmaxf(yv[i], 0.f), 1.f);
        const float q = fmaf(x, x, y * y);               // x^2 + y^2
        const float p = x * y;
#pragma unroll
        for (int r = 0; r < TILE_ROWS; ++r) {
            const int t = i - r;
            if (t >= 0 && t <= 10) {
                const float w = GW[t];
                a0[r] = fmaf(w, x, a0[r]);
                a1[r] = fmaf(w, y, a1[r]);
                a2[r] = fmaf(w, q, a2[r]);
                a3[r] = fmaf(w, p, a3[r]);
            }
        }
    }
#pragma unroll
    for (int r = 0; r < TILE_ROWS; ++r) {
        vbuf[0][r][v] = (_Float16)a0[r];
        vbuf[1][r][v] = (_Float16)a1[r];
        vbuf[2][r][v] = (_Float16)a2[r];
        vbuf[3][r][v] = (_Float16)a3[r];
    }
}

__global__ __launch_bounds__(NTHREADS, 4)
void ssim_fused(const float* __restrict__ den, const float* __restrict__ cln,
                double* __restrict__ slots) {
    __shared__ __align__(16) _Float16 vbuf[NCH][TILE_ROWS][VSTRIDE2]; // 17,408 B
    __shared__ float red[NTHREADS/64];

    const int tid = threadIdx.x;
    const int b  = blockIdx.x;
    const int cs    = b & 1;          // 2 col strips
    const int rs    = (b >> 1) & 63;  // 64 row strips
    const int plane = b >> 7;         // 96 planes

    const int c0 = cs * TILE_COLS;
    const int y0 = rs * TILE_ROWS;
    const size_t pbase = (size_t)plane * (IMG_H * IMG_W);

    // ---- vertical stage: 266 cols over 256 threads (threads 0..9 do two) ----
    vertical_col(tid, c0, y0, pbase, den, cln, vbuf);
    if (tid < VCOLS - NTHREADS)
        vertical_col(NTHREADS + tid, c0, y0, pbase, den, cln, vbuf);
    __syncthreads();

    // ---- horizontal stage + SSIM: 512 items = exactly 2 per thread ----
    float ssim_acc = 0.f;
#pragma unroll
    for (int s = 0; s < 2; ++s) {
        const int item = tid + NTHREADS * s;
        const int row = item >> 6;          // 0..7
        const int j4  = (item & 63) << 2;   // start col in vbuf (halfs, 8B-aligned)
        float bx[4], by[4], bq[4], bp[4];
        hconv4h(&vbuf[0][row][j4], bx);
        hconv4h(&vbuf[1][row][j4], by);
        hconv4h(&vbuf[2][row][j4], bq);
        hconv4h(&vbuf[3][row][j4], bp);
#pragma unroll
        for (int o = 0; o < 4; ++o) {
            const float C1 = 1e-4f, C2 = 9e-4f;
            const float mu1 = bx[o], mu2 = by[o];
            const float mu1s = mu1*mu1, mu2s = mu2*mu2, mu12 = mu1*mu2;
            const float ssum = bq[o] - mu1s - mu2s;   // sigma1_sq + sigma2_sq
            const float s12  = bp[o] - mu12;
            const float num = fmaf(2.f, mu12, C1) * fmaf(2.f, s12, C2);
            const float dnm = (mu1s + mu2s + C1) * (ssum + C2);
            ssim_acc = fmaf(num, __builtin_amdgcn_rcpf(dnm), ssim_acc);
        }
    }

    // ---- block reduction, one f64 atomic per block into a hashed slot ----
#pragma unroll
    for (int off = 32; off > 0; off >>= 1)
        ssim_acc += __shfl_down(ssim_acc, off, 64);
    if ((tid & 63) == 0) red[tid >> 6] = ssim_acc;
    __syncthreads();
    if (tid == 0) {
        const float s = red[0] + red[1] + red[2] + red[3];
        atomicAdd(&slots[(size_t)(b & (NSLOTS - 1)) * 8], (double)s);
    }
}

__global__ void ssim_finalize(const double* __restrict__ slots, float* __restrict__ out,
                              double inv_n) {
    double s = 0.0;
    for (int i = 0; i < NSLOTS; ++i) s += slots[i * 8];
    out[0] = 1.0f - (float)(s * inv_n);
}

extern "C" void kernel_launch(void* const* d_in, const int* in_sizes, int n_in,
                              void* d_out, int out_size, void* d_ws, size_t ws_size,
                              hipStream_t stream) {
    const float* den = (const float*)d_in[0];
    const float* cln = (const float*)d_in[1];
    float* out = (float*)d_out;
    double* slots = (double*)d_ws;

    hipMemsetAsync(d_ws, 0, NSLOTS * 64, stream);

    const int n = in_sizes[0];                 // 32*3*512*512
    const int planes = n / (IMG_H * IMG_W);    // 96
    dim3 grid(planes * 2 * 64);                // 2 col strips x 64 row strips
    ssim_fused<<<grid, NTHREADS, 0, stream>>>(den, cln, slots);
    ssim_finalize<<<1, 1, 0, stream>>>(slots, out, 1.0 / (double)n);
}